// Round 2
// baseline (15206.503 us; speedup 1.0000x reference)
//
#include <hip/hip_runtime.h>
#include <stdint.h>

typedef __attribute__((ext_vector_type(8))) short short8;
typedef __attribute__((ext_vector_type(4))) float f32x4;
typedef __attribute__((ext_vector_type(4))) unsigned short u16x4;
typedef unsigned short ushort_t;

// ---------- helpers ----------
__device__ __forceinline__ unsigned short f2b(float f){           // f32 -> bf16 RNE
  uint32_t u = __float_as_uint(f);
  u = (u + 0x7FFFu + ((u >> 16) & 1u)) >> 16;
  return (unsigned short)u;
}
__device__ __forceinline__ float b2f(unsigned short h){
  uint32_t u = ((uint32_t)h) << 16;
  return __uint_as_float(u);
}
__device__ __forceinline__ void split2(float v, ushort_t& hi, ushort_t& lo){
  hi = f2b(v);
  lo = f2b(v - b2f(hi));
}
__device__ __forceinline__ unsigned encf(float x){                // monotonic f32->u32
  uint32_t u = __float_as_uint(x);
  return (u & 0x80000000u) ? ~u : (u | 0x80000000u);
}
__device__ __forceinline__ float decf(unsigned u){
  uint32_t b = (u & 0x80000000u) ? (u & 0x7FFFFFFFu) : ~u;
  return __uint_as_float(b);
}

// ---------- small utility kernels ----------
__global__ __launch_bounds__(256) void zero_u32(unsigned* __restrict__ p, int n){
  for (int i = blockIdx.x*256 + threadIdx.x; i < n; i += gridDim.x*256) p[i] = 0u;
}

// w (f32, [CO][CI][3][3]) -> wp (bf16 split, [9][COUTP][2*CINP]): hi at ci, lo at CINP+ci
__global__ __launch_bounds__(256) void pack_w(const float* __restrict__ w, ushort_t* __restrict__ wp,
                                              int CO, int CI, int COUTP, int CINP){
  int idx = blockIdx.x*256 + threadIdx.x;
  int total = 9*COUTP*CINP;
  if (idx >= total) return;
  int ci = idx % CINP;
  int rest = idx / CINP;
  int co = rest % COUTP;
  int t  = rest / COUTP;
  float v = 0.f;
  if (co < CO && ci < CI) v = w[((size_t)co*CI + ci)*9 + t];
  ushort_t hi, lo; split2(v, hi, lo);
  size_t base = ((size_t)t*COUTP + co)*(2*CINP);
  wp[base + ci]        = hi;
  wp[base + CINP + ci] = lo;
}

__global__ __launch_bounds__(256) void pack_bias(const float* __restrict__ b, float* __restrict__ bp, int n, int npad){
  int i = blockIdx.x*256 + threadIdx.x;
  if (i < npad) bp[i] = (i < n) ? b[i] : 0.f;
}

// features f32 [16][36864] -> rnn_in ch0..15 (hi)/160..175 (lo), k1_in ch128..143/288..303
// if copy_state: k1_in ch0..127 + 160..287 (state hi/lo) -> rnn_in ch16..143 + 176..303
__global__ __launch_bounds__(256) void pack_feat(const float* __restrict__ f,
                                                 ushort_t* __restrict__ rnn_in,
                                                 ushort_t* __restrict__ k1_in,
                                                 int copy_state){
  int p = blockIdx.x*256 + threadIdx.x;
  if (p >= 36864) return;
  ushort_t* r = rnn_in + (size_t)p*320;
  ushort_t* k = k1_in  + (size_t)p*320;
  #pragma unroll
  for (int c = 0; c < 16; ++c){
    ushort_t hi, lo; split2(f[c*36864 + p], hi, lo);
    r[c]       = hi;  r[160 + c] = lo;
    k[128 + c] = hi;  k[288 + c] = lo;
  }
  if (copy_state){
    #pragma unroll
    for (int cc = 0; cc < 128; cc += 8){
      *reinterpret_cast<short8*>(r + 16  + cc) = *reinterpret_cast<const short8*>(k + cc);
      *reinterpret_cast<short8*>(r + 176 + cc) = *reinterpret_cast<const short8*>(k + 160 + cc);
    }
  }
}

// ---------- conv3x3 via split-bf16 MFMA (implicit GEMM, ~fp32 accurate) ----------
// block = 256 threads = 4 waves: (wm: cout half) x (wq: row pair)
// block tile: 64 cout x (4 rows x 32 cols). wave tile: 32 cout x (2 rows x 32 cols)
// X: NHWC bf16 [H][W][2*CINP] (hi | lo); Wp: bf16 [9][COUTP][2*CINP]
// !K3: Y NHWC bf16 [Ho][Wo][2*DCP], hi at ch cb, lo at ch DCP+cb, optional leaky-relu
//  K3: Y32 f32 planes [t][Ho][Wo] (t<441) + wave-reduced atomicMax of outputs
template<int CINP, int PAD, bool RELU, bool K3>
__global__ __launch_bounds__(256) void conv3(
    const ushort_t* __restrict__ X, int H, int W,
    const ushort_t* __restrict__ Wp, int COUTP,
    const float* __restrict__ bias,
    ushort_t* __restrict__ Y, int DCP,
    float* __restrict__ Y32, unsigned* __restrict__ slot,
    int Ho, int Wo)
{
  constexpr int C2 = 2*CINP;
  constexpr int KC = CINP/32;
  const int tid  = threadIdx.x;
  const int lane = tid & 63;
  const int wid  = tid >> 6;
  const int wm   = wid & 1;
  const int wq   = wid >> 1;
  const int l15  = lane & 15, lg = lane >> 4;
  const int x0   = blockIdx.x * 32;
  const int y0   = blockIdx.y * 4 + wq*2;
  const int co_base = blockIdx.z * 64 + wm * 32;

  f32x4 acc[2][4] = {};

  const ushort_t* wbase = Wp + (size_t)(co_base + l15) * C2;
  const int wstep = COUTP * C2;

  for (int ky = 0; ky < 3; ++ky){
    for (int kx = 0; kx < 3; ++kx){
      const ushort_t* wt = wbase + (size_t)(ky*3+kx) * wstep;
      const ushort_t* bp[4];
      bool bv[4];
      #pragma unroll
      for (int n = 0; n < 4; ++n){
        int yi = y0 + (n>>1) + ky - PAD;
        int xi = x0 + (n&1)*16 + l15 + kx - PAD;
        if (PAD){
          bool v = ((unsigned)yi < (unsigned)H) && ((unsigned)xi < (unsigned)W);
          bv[n] = v;
          if (!v){ yi = 0; xi = 0; }
        } else {
          yi = min(yi, H-1);   // only affects store-masked (dead) outputs
          xi = min(xi, W-1);
          bv[n] = true;
        }
        bp[n] = X + ((size_t)yi*W + xi)*C2;
      }
      #pragma unroll
      for (int kc = 0; kc < KC; ++kc){
        const int koff = kc*32 + lg*8;
        short8 ah0 = *reinterpret_cast<const short8*>(wt + koff);
        short8 al0 = *reinterpret_cast<const short8*>(wt + CINP + koff);
        short8 ah1 = *reinterpret_cast<const short8*>(wt + 16*C2 + koff);
        short8 al1 = *reinterpret_cast<const short8*>(wt + 16*C2 + CINP + koff);
        #pragma unroll
        for (int n = 0; n < 4; ++n){
          short8 bh = *reinterpret_cast<const short8*>(bp[n] + koff);
          short8 bl = *reinterpret_cast<const short8*>(bp[n] + CINP + koff);
          if (PAD && !bv[n]){ short8 z = {0,0,0,0,0,0,0,0}; bh = z; bl = z; }
          acc[0][n] = __builtin_amdgcn_mfma_f32_16x16x32_bf16(ah0, bh, acc[0][n], 0, 0, 0);
          acc[1][n] = __builtin_amdgcn_mfma_f32_16x16x32_bf16(ah1, bh, acc[1][n], 0, 0, 0);
          acc[0][n] = __builtin_amdgcn_mfma_f32_16x16x32_bf16(al0, bh, acc[0][n], 0, 0, 0);
          acc[1][n] = __builtin_amdgcn_mfma_f32_16x16x32_bf16(al1, bh, acc[1][n], 0, 0, 0);
          acc[0][n] = __builtin_amdgcn_mfma_f32_16x16x32_bf16(ah0, bl, acc[0][n], 0, 0, 0);
          acc[1][n] = __builtin_amdgcn_mfma_f32_16x16x32_bf16(ah1, bl, acc[1][n], 0, 0, 0);
        }
      }
    }
  }

  float lmax = -3.0e38f;
  #pragma unroll
  for (int m = 0; m < 2; ++m){
    const int cb = co_base + m*16 + lg*4;       // 4 consecutive output channels
    f32x4 bs = *reinterpret_cast<const f32x4*>(bias + cb);
    #pragma unroll
    for (int n = 0; n < 4; ++n){
      const int yo = y0 + (n>>1);
      const int xo = x0 + (n&1)*16 + l15;
      float v[4];
      #pragma unroll
      for (int j = 0; j < 4; ++j){
        float t = acc[m][n][j] + bs[j];
        if (RELU) t = t > 0.f ? t : 0.01f*t;
        v[j] = t;
      }
      if (yo < Ho && xo < Wo){
        if constexpr (!K3){
          u16x4 ph, pl;
          #pragma unroll
          for (int j = 0; j < 4; ++j){
            ushort_t hi, lo; split2(v[j], hi, lo);
            ph[j] = hi; pl[j] = lo;
          }
          ushort_t* yp = Y + ((size_t)yo*Wo + xo)*(2*DCP);
          *reinterpret_cast<u16x4*>(yp + cb)       = ph;
          *reinterpret_cast<u16x4*>(yp + DCP + cb) = pl;
        } else {
          #pragma unroll
          for (int j = 0; j < 4; ++j){
            if (cb + j < 441){
              Y32[(size_t)(cb+j)*(Ho*Wo) + (size_t)yo*Wo + xo] = v[j];
              lmax = fmaxf(lmax, v[j]);
            }
          }
        }
      }
    }
  }
  if constexpr (K3){
    #pragma unroll
    for (int o = 32; o > 0; o >>= 1) lmax = fmaxf(lmax, __shfl_xor(lmax, o));
    if (lane == 0) atomicMax(slot, encf(lmax));
  }
}

// streaming-max state update: st[0]=M, st[1]=scale=exp(M_old-M_new); resets slot
__global__ void update_max(float* __restrict__ st, unsigned* __restrict__ slot, int step){
  if (threadIdx.x == 0){
    float nm   = decf(*slot);
    float oldM = st[0];
    float M    = (step == 0) ? nm : fmaxf(oldM, nm);
    st[1] = (step == 0) ? 0.f : expf(oldM - M);
    st[0] = M;
    *slot = 0u;
  }
}

// per-pixel: w_t = exp(k3[t][y+7][x+7]-M); unnorm = unnorm*scale + sum_t w_t*rad[ci][y+dy][x+dx]
__global__ __launch_bounds__(256) void apply_acc(
    const float* __restrict__ k3out, const float* __restrict__ rad,
    const float* __restrict__ st,
    float* __restrict__ unnorm, float* __restrict__ sumw)
{
  const int tx = threadIdx.x & 63, ty = threadIdx.x >> 6;
  const int x = blockIdx.x*64 + tx;
  const int y = blockIdx.y*4 + ty;
  if (x >= 172 || y >= 172) return;
  const float M = st[0], scale = st[1];
  float a0 = 0.f, a1 = 0.f, a2 = 0.f, aw = 0.f;
  const float* kp = k3out + (size_t)(y+7)*186 + (x+7);
  for (int dy = 0; dy < 21; ++dy){
    const float* r0 = rad + (size_t)(y+dy)*192 + x;
    #pragma unroll
    for (int dx = 0; dx < 21; ++dx){
      float w = __expf(kp[(size_t)(dy*21+dx)*34596] - M);
      aw += w;
      a0 += w * r0[dx];
      a1 += w * r0[36864 + dx];
      a2 += w * r0[73728 + dx];
    }
  }
  size_t p = (size_t)y*172 + x;
  unnorm[p]        = unnorm[p]*scale        + a0;
  unnorm[p+29584]  = unnorm[p+29584]*scale  + a1;
  unnorm[p+59168]  = unnorm[p+59168]*scale  + a2;
  sumw[p]          = sumw[p]*scale          + aw;
}

__global__ __launch_bounds__(256) void finalize_out(const float* __restrict__ unnorm,
                                                    const float* __restrict__ sumw,
                                                    float* __restrict__ out){
  int i = blockIdx.x*256 + threadIdx.x;
  if (i >= 88752) return;
  int p = i % 29584;
  out[i] = unnorm[i] / (sumw[p] + 1e-8f);
}

// ---------- host ----------
extern "C" void kernel_launch(void* const* d_in, const int* in_sizes, int n_in,
                              void* d_out, int out_size, void* d_ws, size_t ws_size,
                              hipStream_t stream) {
  const float* features = (const float*)d_in[0];
  const float* radiance = (const float*)d_in[1];
  const float* w_rnn = (const float*)d_in[2];
  const float* b_rnn = (const float*)d_in[3];
  const float* w_k1  = (const float*)d_in[4];
  const float* b_k1  = (const float*)d_in[5];
  const float* w_k2  = (const float*)d_in[6];
  const float* b_k2  = (const float*)d_in[7];
  const float* w_k3  = (const float*)d_in[8];
  const float* b_k3  = (const float*)d_in[9];
  float* out = (float*)d_out;

  char* ws = (char*)d_ws;
  size_t off = 0;
  auto alloc = [&](size_t bytes)->char*{
    char* p = ws + off;
    off = (off + bytes + 255) & ~(size_t)255;
    return p;
  };
  ushort_t* wp_rnn   = (ushort_t*)alloc((size_t)9*128*320*2);
  ushort_t* wp_k1    = (ushort_t*)alloc((size_t)9*128*320*2);
  ushort_t* wp_k2    = (ushort_t*)alloc((size_t)9*128*256*2);
  ushort_t* wp_k3    = (ushort_t*)alloc((size_t)9*448*256*2);
  float*    bias_k3p = (float*)   alloc((size_t)448*4);
  ushort_t* rnn_in   = (ushort_t*)alloc((size_t)36864*320*2);
  ushort_t* k1_in    = (ushort_t*)alloc((size_t)36864*320*2);
  ushort_t* k2_in    = (ushort_t*)alloc((size_t)190*190*256*2);
  ushort_t* k3_in    = (ushort_t*)alloc((size_t)188*188*256*2);
  float*    k3_out   = (float*)   alloc((size_t)441*34596*4);
  float*    acc_zone = (float*)   alloc((size_t)118339*4);
  if (off > ws_size) return;  // workspace too small -> fail loudly (no OOB writes)

  float*    unnorm = acc_zone;            // [3][172][172]
  float*    sumw   = acc_zone + 88752;    // [172][172]
  float*    st     = acc_zone + 118336;   // {M, scale}
  unsigned* slot   = (unsigned*)(acc_zone + 118338);

  // weight prepack (pure function of inputs; runs every call)
  pack_w<<<(9*128*160+255)/256, 256, 0, stream>>>(w_rnn, wp_rnn, 128, 144, 128, 160);
  pack_w<<<(9*128*160+255)/256, 256, 0, stream>>>(w_k1,  wp_k1,  128, 144, 128, 160);
  pack_w<<<(9*128*128+255)/256, 256, 0, stream>>>(w_k2,  wp_k2,  128, 128, 128, 128);
  pack_w<<<(9*448*128+255)/256, 256, 0, stream>>>(w_k3,  wp_k3,  441, 128, 448, 128);
  pack_bias<<<2, 256, 0, stream>>>(b_k3, bias_k3p, 441, 448);

  for (int b = 0; b < 2; ++b){
    zero_u32<<<2048, 256, 0, stream>>>((unsigned*)rnn_in, 5898240);
    zero_u32<<<2048, 256, 0, stream>>>((unsigned*)k1_in,  5898240);
    zero_u32<<<464,  256, 0, stream>>>((unsigned*)acc_zone, 118339);
    for (int s = 0; s < 8; ++s){
      const float* f   = features + ((size_t)(b*8 + s)*16)*36864;
      const float* rad = radiance + ((size_t)(b*8 + s)*3 )*36864;
      pack_feat<<<144, 256, 0, stream>>>(f, rnn_in, k1_in, s > 0 ? 1 : 0);
      // rnn: 144->128, SAME, lrelu; out -> k1_in ch0..127 (+lo at 160..287)
      conv3<160,1,true ,false><<<dim3(6,48,2), 256, 0, stream>>>(
          rnn_in, 192, 192, wp_rnn, 128, b_rnn, k1_in, 160, nullptr, nullptr, 192, 192);
      // k1: 144->128, VALID, lrelu; out -> k2_in (190x190)
      conv3<160,0,true ,false><<<dim3(6,48,2), 256, 0, stream>>>(
          k1_in, 192, 192, wp_k1, 128, b_k1, k2_in, 128, nullptr, nullptr, 190, 190);
      // k2: 128->128, VALID, lrelu; out -> k3_in (188x188)
      conv3<128,0,true ,false><<<dim3(6,47,2), 256, 0, stream>>>(
          k2_in, 190, 190, wp_k2, 128, b_k2, k3_in, 128, nullptr, nullptr, 188, 188);
      // k3: 128->441(448), VALID, no relu; out -> f32 planes + atomic max
      conv3<128,0,false,true ><<<dim3(6,47,7), 256, 0, stream>>>(
          k3_in, 188, 188, wp_k3, 448, bias_k3p, nullptr, 0, k3_out, slot, 186, 186);
      update_max<<<1, 64, 0, stream>>>(st, slot, s);
      apply_acc<<<dim3(3,43), 256, 0, stream>>>(k3_out, rad, st, unnorm, sumw);
    }
    finalize_out<<<347, 256, 0, stream>>>(unnorm, sumw, out + (size_t)b*88752);
  }
}

// Round 3
// 8824.156 us; speedup vs baseline: 1.7233x; 1.7233x over previous
//
#include <hip/hip_runtime.h>
#include <stdint.h>

typedef __attribute__((ext_vector_type(8))) short short8;
typedef __attribute__((ext_vector_type(4))) float f32x4;
typedef __attribute__((ext_vector_type(4))) unsigned short u16x4;
typedef unsigned short ushort_t;

// ---------- helpers ----------
__device__ __forceinline__ unsigned short f2b(float f){           // f32 -> bf16 RNE
  uint32_t u = __float_as_uint(f);
  u = (u + 0x7FFFu + ((u >> 16) & 1u)) >> 16;
  return (unsigned short)u;
}
__device__ __forceinline__ float b2f(unsigned short h){
  uint32_t u = ((uint32_t)h) << 16;
  return __uint_as_float(u);
}
__device__ __forceinline__ void split2(float v, ushort_t& hi, ushort_t& lo){
  hi = f2b(v);
  lo = f2b(v - b2f(hi));
}
__device__ __forceinline__ unsigned encf(float x){                // monotonic f32->u32
  uint32_t u = __float_as_uint(x);
  return (u & 0x80000000u) ? ~u : (u | 0x80000000u);
}
__device__ __forceinline__ float decf(unsigned u){
  uint32_t b = (u & 0x80000000u) ? (u & 0x7FFFFFFFu) : ~u;
  return __uint_as_float(b);
}
__device__ __forceinline__ void gload16(const void* g, void* l){
  __builtin_amdgcn_global_load_lds(
      (const __attribute__((address_space(1))) void*)g,
      (__attribute__((address_space(3))) void*)l, 16, 0, 0);
}

// ---------- small utility kernels ----------
__global__ __launch_bounds__(256) void zero_u32(unsigned* __restrict__ p, int n){
  for (int i = blockIdx.x*256 + threadIdx.x; i < n; i += gridDim.x*256) p[i] = 0u;
}

// w (f32, [CO][CI][3][3]) -> wp (bf16 split, [9][COUTP][2*CINP]): hi at ci, lo at CINP+ci
__global__ __launch_bounds__(256) void pack_w(const float* __restrict__ w, ushort_t* __restrict__ wp,
                                              int CO, int CI, int COUTP, int CINP){
  int idx = blockIdx.x*256 + threadIdx.x;
  int total = 9*COUTP*CINP;
  if (idx >= total) return;
  int ci = idx % CINP;
  int rest = idx / CINP;
  int co = rest % COUTP;
  int t  = rest / COUTP;
  float v = 0.f;
  if (co < CO && ci < CI) v = w[((size_t)co*CI + ci)*9 + t];
  ushort_t hi, lo; split2(v, hi, lo);
  size_t base = ((size_t)t*COUTP + co)*(2*CINP);
  wp[base + ci]        = hi;
  wp[base + CINP + ci] = lo;
}

__global__ __launch_bounds__(256) void pack_bias(const float* __restrict__ b, float* __restrict__ bp, int n, int npad){
  int i = blockIdx.x*256 + threadIdx.x;
  if (i < npad) bp[i] = (i < n) ? b[i] : 0.f;
}

// features f32 [16][36864] -> rnn_in (halo 194x194, interior at +1,+1) ch0..15/160..175
//                           k1_in (192x192) ch128..143/288..303
// if copy_state: k1_in ch0..127 + 160..287 (state hi/lo) -> rnn_in ch16..143 + 176..303
__global__ __launch_bounds__(256) void pack_feat(const float* __restrict__ f,
                                                 ushort_t* __restrict__ rnn_in,
                                                 ushort_t* __restrict__ k1_in,
                                                 int copy_state){
  int p = blockIdx.x*256 + threadIdx.x;
  if (p >= 36864) return;
  int y = p / 192, x = p % 192;
  ushort_t* r = rnn_in + ((size_t)(y+1)*194 + (x+1))*320;
  ushort_t* k = k1_in  + (size_t)p*320;
  #pragma unroll
  for (int c = 0; c < 16; ++c){
    ushort_t hi, lo; split2(f[c*36864 + p], hi, lo);
    r[c]       = hi;  r[160 + c] = lo;
    k[128 + c] = hi;  k[288 + c] = lo;
  }
  if (copy_state){
    #pragma unroll
    for (int cc = 0; cc < 128; cc += 8){
      *reinterpret_cast<short8*>(r + 16  + cc) = *reinterpret_cast<const short8*>(k + cc);
      *reinterpret_cast<short8*>(r + 176 + cc) = *reinterpret_cast<const short8*>(k + 160 + cc);
    }
  }
}

// ---------- conv3x3: LDS-staged split-bf16 implicit GEMM ----------
// block = 256 threads = 4 waves; wave wid owns output row yb+wid.
// block tile: 64 couts x 4 rows x 64 cols. wave tile: 64 couts x 1 row x 64 cols.
// LDS: one 32-ch chunk (hi+lo) of the 6x66 input halo tile:
//   layout [plane2][row6][sg4][col66][8ch] (16B granules, lane-contiguous ds_read_b128)
// staged via global_load_lds (per-lane global gather -> linear LDS).
// All convs are VALID-style (rnn uses a pre-zeroed halo buffer); edge reads land in
// allocation slack and only feed store-masked dead outputs.
template<int CINP, bool RELU, bool K3>
__global__ __launch_bounds__(256, 2) void conv3(
    const ushort_t* __restrict__ X, int Wst,
    const ushort_t* __restrict__ Wp, int COUTP,
    const float* __restrict__ bias,
    ushort_t* __restrict__ Y, int Wst_out, int DCP,
    float* __restrict__ Y32, unsigned* __restrict__ slot,
    int Ho, int Wo)
{
  constexpr int C2 = 2*CINP;
  constexpr int KC = CINP/32;
  __shared__ ushort_t lds[25344];          // 50688 B: 2 planes x 6 rows x 4 sg x 66 cols x 16B

  const int tid  = threadIdx.x;
  const int lane = tid & 63;
  const int wid  = tid >> 6;
  const int l15  = lane & 15, lg = lane >> 4;
  const int xb   = blockIdx.x * 64;
  const int yb   = blockIdx.y * 4;
  const int co_base = blockIdx.z * 64;

  // ---- per-thread stage addresses (kc=0), 3168 16B-items over 13 rounds ----
  uint32_t goff[13];
  #pragma unroll
  for (int k = 0; k < 13; ++k){
    int item = k*256 + tid;
    if (item < 3168){
      int col = item % 66;
      int q   = item / 66;
      int sg  = q & 3; q >>= 2;
      int row = q % 6;
      int plane = q / 6;
      int pix = (yb + row)*Wst + xb + col;
      goff[k] = (uint32_t)(((size_t)pix*C2 + (size_t)plane*CINP + sg*8) * 2);
    } else {
      goff[k] = 0;
    }
  }

  auto stage = [&](int kc){
    const char* xp = (const char*)X + kc*64;   // advance 32 channels = 64 B
    #pragma unroll
    for (int k = 0; k < 13; ++k){
      if (k*256 + tid < 3168){
        gload16(xp + goff[k], (char*)lds + k*4096 + wid*1024);
      }
    }
  };

  f32x4 acc[4][4] = {};

  const ushort_t* wlane = Wp + (size_t)(co_base + l15)*C2 + lg*8;

  stage(0);
  for (int kc = 0; kc < KC; ++kc){
    __syncthreads();                         // staged chunk visible
    for (int ky = 0; ky < 3; ++ky){
      for (int kx = 0; kx < 3; ++kx){
        const ushort_t* wt = wlane + (size_t)(ky*3+kx)*COUTP*C2 + kc*32;
        short8 ah[4], al[4];
        #pragma unroll
        for (int i = 0; i < 4; ++i){
          ah[i] = *reinterpret_cast<const short8*>(wt + (size_t)i*16*C2);
          al[i] = *reinterpret_cast<const short8*>(wt + (size_t)i*16*C2 + CINP);
        }
        const int ldsrow = ((wid + ky)*4 + lg)*66;
        #pragma unroll
        for (int n = 0; n < 4; ++n){
          const int ui = (ldsrow + n*16 + l15 + kx)*8;
          short8 bh = *reinterpret_cast<const short8*>(lds + ui);
          short8 bl = *reinterpret_cast<const short8*>(lds + 12672 + ui);
          #pragma unroll
          for (int i = 0; i < 4; ++i)
            acc[i][n] = __builtin_amdgcn_mfma_f32_16x16x32_bf16(ah[i], bh, acc[i][n], 0, 0, 0);
          #pragma unroll
          for (int i = 0; i < 4; ++i)
            acc[i][n] = __builtin_amdgcn_mfma_f32_16x16x32_bf16(al[i], bh, acc[i][n], 0, 0, 0);
          #pragma unroll
          for (int i = 0; i < 4; ++i)
            acc[i][n] = __builtin_amdgcn_mfma_f32_16x16x32_bf16(ah[i], bl, acc[i][n], 0, 0, 0);
        }
      }
    }
    __syncthreads();                         // all reads done before restage
    if (kc + 1 < KC) stage(kc + 1);
  }

  // ---- epilogue ----
  const int y = yb + wid;
  float lmax = -3.0e38f;
  if (y < Ho){
    #pragma unroll
    for (int i = 0; i < 4; ++i){
      const int cb = co_base + i*16 + lg*4;      // 4 consecutive output channels
      f32x4 bs = *reinterpret_cast<const f32x4*>(bias + cb);
      #pragma unroll
      for (int n = 0; n < 4; ++n){
        const int x = xb + n*16 + l15;
        if (x < Wo){
          float v[4];
          #pragma unroll
          for (int j = 0; j < 4; ++j){
            float t = acc[i][n][j] + bs[j];
            if (RELU) t = t > 0.f ? t : 0.01f*t;
            v[j] = t;
          }
          if constexpr (!K3){
            u16x4 ph, pl;
            #pragma unroll
            for (int j = 0; j < 4; ++j){
              ushort_t hi, lo; split2(v[j], hi, lo);
              ph[j] = hi; pl[j] = lo;
            }
            ushort_t* yp = Y + ((size_t)y*Wst_out + x)*(2*DCP);
            *reinterpret_cast<u16x4*>(yp + cb)       = ph;
            *reinterpret_cast<u16x4*>(yp + DCP + cb) = pl;
          } else {
            #pragma unroll
            for (int j = 0; j < 4; ++j){
              if (cb + j < 441){
                Y32[(size_t)(cb+j)*34596 + (size_t)y*186 + x] = v[j];
                lmax = fmaxf(lmax, v[j]);
              }
            }
          }
        }
      }
    }
  }
  if constexpr (K3){
    #pragma unroll
    for (int o = 32; o > 0; o >>= 1) lmax = fmaxf(lmax, __shfl_xor(lmax, o));
    if (lane == 0) atomicMax(slot, encf(lmax));
  }
}

// streaming-max state update: st[0]=M, st[1]=scale=exp(M_old-M_new); resets slot
__global__ void update_max(float* __restrict__ st, unsigned* __restrict__ slot, int step){
  if (threadIdx.x == 0){
    float nm   = decf(*slot);
    float oldM = st[0];
    float M    = (step == 0) ? nm : fmaxf(oldM, nm);
    st[1] = (step == 0) ? 0.f : expf(oldM - M);
    st[0] = M;
    *slot = 0u;
  }
}

// per-pixel: w_t = exp(k3[t][y+7][x+7]-M); unnorm = unnorm*scale + sum_t w_t*rad[ci][y+dy][x+dx]
__global__ __launch_bounds__(256) void apply_acc(
    const float* __restrict__ k3out, const float* __restrict__ rad,
    const float* __restrict__ st,
    float* __restrict__ unnorm, float* __restrict__ sumw)
{
  const int tx = threadIdx.x & 63, ty = threadIdx.x >> 6;
  const int x = blockIdx.x*64 + tx;
  const int y = blockIdx.y*4 + ty;
  if (x >= 172 || y >= 172) return;
  const float M = st[0], scale = st[1];
  float a0 = 0.f, a1 = 0.f, a2 = 0.f, aw = 0.f;
  const float* kp = k3out + (size_t)(y+7)*186 + (x+7);
  for (int dy = 0; dy < 21; ++dy){
    const float* r0 = rad + (size_t)(y+dy)*192 + x;
    #pragma unroll
    for (int dx = 0; dx < 21; ++dx){
      float w = __expf(kp[(size_t)(dy*21+dx)*34596] - M);
      aw += w;
      a0 += w * r0[dx];
      a1 += w * r0[36864 + dx];
      a2 += w * r0[73728 + dx];
    }
  }
  size_t p = (size_t)y*172 + x;
  unnorm[p]        = unnorm[p]*scale        + a0;
  unnorm[p+29584]  = unnorm[p+29584]*scale  + a1;
  unnorm[p+59168]  = unnorm[p+59168]*scale  + a2;
  sumw[p]          = sumw[p]*scale          + aw;
}

__global__ __launch_bounds__(256) void finalize_out(const float* __restrict__ unnorm,
                                                    const float* __restrict__ sumw,
                                                    float* __restrict__ out){
  int i = blockIdx.x*256 + threadIdx.x;
  if (i >= 88752) return;
  int p = i % 29584;
  out[i] = unnorm[i] / (sumw[p] + 1e-8f);
}

// ---------- host ----------
extern "C" void kernel_launch(void* const* d_in, const int* in_sizes, int n_in,
                              void* d_out, int out_size, void* d_ws, size_t ws_size,
                              hipStream_t stream) {
  const float* features = (const float*)d_in[0];
  const float* radiance = (const float*)d_in[1];
  const float* w_rnn = (const float*)d_in[2];
  const float* b_rnn = (const float*)d_in[3];
  const float* w_k1  = (const float*)d_in[4];
  const float* b_k1  = (const float*)d_in[5];
  const float* w_k2  = (const float*)d_in[6];
  const float* b_k2  = (const float*)d_in[7];
  const float* w_k3  = (const float*)d_in[8];
  const float* b_k3  = (const float*)d_in[9];
  float* out = (float*)d_out;

  char* ws = (char*)d_ws;
  size_t off = 0;
  auto alloc = [&](size_t bytes)->char*{
    char* p = ws + off;
    off = (off + bytes + 255) & ~(size_t)255;
    return p;
  };
  ushort_t* wp_rnn   = (ushort_t*)alloc((size_t)9*128*320*2);
  ushort_t* wp_k1    = (ushort_t*)alloc((size_t)9*128*320*2);
  ushort_t* wp_k2    = (ushort_t*)alloc((size_t)9*128*256*2);
  ushort_t* wp_k3    = (ushort_t*)alloc((size_t)9*448*256*2);
  float*    bias_k3p = (float*)   alloc((size_t)448*4);
  ushort_t* rnn_in   = (ushort_t*)alloc((size_t)194*194*320*2);            // halo
  ushort_t* k1_in    = (ushort_t*)alloc((size_t)(192*192+448)*320*2);      // +slack
  ushort_t* k2_in    = (ushort_t*)alloc((size_t)(190*190+444)*256*2);      // +slack
  ushort_t* k3_in    = (ushort_t*)alloc((size_t)(188*188+440)*256*2);      // +slack
  float*    k3_out   = (float*)   alloc((size_t)441*34596*4);
  float*    acc_zone = (float*)   alloc((size_t)118339*4);
  if (off > ws_size) return;  // workspace too small -> fail loudly (no OOB writes)

  float*    unnorm = acc_zone;            // [3][172][172]
  float*    sumw   = acc_zone + 88752;    // [172][172]
  float*    st     = acc_zone + 118336;   // {M, scale}
  unsigned* slot   = (unsigned*)(acc_zone + 118338);

  // weight prepack (pure function of inputs; runs every call)
  pack_w<<<(9*128*160+255)/256, 256, 0, stream>>>(w_rnn, wp_rnn, 128, 144, 128, 160);
  pack_w<<<(9*128*160+255)/256, 256, 0, stream>>>(w_k1,  wp_k1,  128, 144, 128, 160);
  pack_w<<<(9*128*128+255)/256, 256, 0, stream>>>(w_k2,  wp_k2,  128, 128, 128, 128);
  pack_w<<<(9*448*128+255)/256, 256, 0, stream>>>(w_k3,  wp_k3,  441, 128, 448, 128);
  pack_bias<<<2, 256, 0, stream>>>(b_k3, bias_k3p, 441, 448);

  for (int b = 0; b < 2; ++b){
    zero_u32<<<2048, 256, 0, stream>>>((unsigned*)rnn_in, 194*194*160);
    zero_u32<<<2048, 256, 0, stream>>>((unsigned*)k1_in,  (192*192+448)*160);
    zero_u32<<<464,  256, 0, stream>>>((unsigned*)acc_zone, 118339);
    for (int s = 0; s < 8; ++s){
      const float* f   = features + ((size_t)(b*8 + s)*16)*36864;
      const float* rad = radiance + ((size_t)(b*8 + s)*3 )*36864;
      pack_feat<<<144, 256, 0, stream>>>(f, rnn_in, k1_in, s > 0 ? 1 : 0);
      // rnn: 144->128 SAME via zero halo (VALID on 194x194), lrelu; -> k1_in ch0..127/160..287
      conv3<160,true ,false><<<dim3(3,48,2), 256, 0, stream>>>(
          rnn_in, 194, wp_rnn, 128, b_rnn, k1_in, 192, 160, nullptr, nullptr, 192, 192);
      // k1: 144->128 VALID, lrelu; -> k2_in (190x190)
      conv3<160,true ,false><<<dim3(3,48,2), 256, 0, stream>>>(
          k1_in, 192, wp_k1, 128, b_k1, k2_in, 190, 128, nullptr, nullptr, 190, 190);
      // k2: 128->128 VALID, lrelu; -> k3_in (188x188)
      conv3<128,true ,false><<<dim3(3,47,2), 256, 0, stream>>>(
          k2_in, 190, wp_k2, 128, b_k2, k3_in, 188, 128, nullptr, nullptr, 188, 188);
      // k3: 128->441(448) VALID, no relu; -> f32 planes + atomic max
      conv3<128,false,true ><<<dim3(3,47,7), 256, 0, stream>>>(
          k3_in, 188, wp_k3, 448, bias_k3p, nullptr, 0, 0, k3_out, slot, 186, 186);
      update_max<<<1, 64, 0, stream>>>(st, slot, s);
      apply_acc<<<dim3(3,43), 256, 0, stream>>>(k3_out, rad, st, unnorm, sumw);
    }
    finalize_out<<<347, 256, 0, stream>>>(unnorm, sumw, out + (size_t)b*88752);
  }
}

// Round 4
// 5124.447 us; speedup vs baseline: 2.9674x; 1.7220x over previous
//
#include <hip/hip_runtime.h>
#include <stdint.h>

typedef _Float16 half8 __attribute__((ext_vector_type(8)));
typedef _Float16 half4 __attribute__((ext_vector_type(4)));
typedef __attribute__((ext_vector_type(8))) short short8;
typedef __attribute__((ext_vector_type(4))) float f32x4;

// ---------- helpers ----------
__device__ __forceinline__ unsigned encf(float x){                // monotonic f32->u32
  uint32_t u = __float_as_uint(x);
  return (u & 0x80000000u) ? ~u : (u | 0x80000000u);
}
__device__ __forceinline__ float decf(unsigned u){
  uint32_t b = (u & 0x80000000u) ? (u & 0x7FFFFFFFu) : ~u;
  return __uint_as_float(b);
}
__device__ __forceinline__ void gload16(const void* g, void* l){
  __builtin_amdgcn_global_load_lds(
      (const __attribute__((address_space(1))) void*)g,
      (__attribute__((address_space(3))) void*)l, 16, 0, 0);
}

// ---------- small utility kernels ----------
__global__ __launch_bounds__(256) void zero_u32(unsigned* __restrict__ p, int n){
  for (int i = blockIdx.x*256 + threadIdx.x; i < n; i += gridDim.x*256) p[i] = 0u;
}

// w (f32, [CO][CI][3][3]) -> wp (fp16, [9][COUTP][CINP]) zero-padded
__global__ __launch_bounds__(256) void pack_w(const float* __restrict__ w, _Float16* __restrict__ wp,
                                              int CO, int CI, int COUTP, int CINP){
  int idx = blockIdx.x*256 + threadIdx.x;
  int total = 9*COUTP*CINP;
  if (idx >= total) return;
  int ci = idx % CINP;
  int rest = idx / CINP;
  int co = rest % COUTP;
  int t  = rest / COUTP;
  float v = 0.f;
  if (co < CO && ci < CI) v = w[((size_t)co*CI + ci)*9 + t];
  wp[idx] = (_Float16)v;
}

__global__ __launch_bounds__(256) void pack_bias(const float* __restrict__ b, float* __restrict__ bp, int n, int npad){
  int i = blockIdx.x*256 + threadIdx.x;
  if (i < npad) bp[i] = (i < n) ? b[i] : 0.f;
}

// features f32 [16][36864] -> rnn_in (halo 194x194, interior at +1,+1) ch0..15
//                             k1_in (192x192) ch128..143
// if copy_state: k1_in ch0..127 (state) -> rnn_in ch16..143. batch = blockIdx.y.
__global__ __launch_bounds__(256) void pack_feat(const float* __restrict__ f,
                                                 _Float16* __restrict__ rnn_in,
                                                 _Float16* __restrict__ k1_in,
                                                 int copy_state,
                                                 unsigned fbstr, unsigned rbstr, unsigned kbstr){
  int p = blockIdx.x*256 + threadIdx.x;
  if (p >= 36864) return;
  int b = blockIdx.y;
  int y = p / 192, x = p % 192;
  const float* fb = f + (size_t)b*fbstr;
  _Float16* r = rnn_in + (size_t)b*rbstr + ((size_t)(y+1)*194 + (x+1))*160;
  _Float16* k = k1_in  + (size_t)b*kbstr + (size_t)p*160;
  #pragma unroll
  for (int c = 0; c < 16; ++c){
    _Float16 v = (_Float16)fb[c*36864 + p];
    r[c] = v;
    k[128 + c] = v;
  }
  if (copy_state){
    #pragma unroll
    for (int cc = 0; cc < 128; cc += 8)
      *reinterpret_cast<short8*>(r + 16 + cc) = *reinterpret_cast<const short8*>(k + cc);
  }
}

// ---------- conv3x3: LDS double-buffered fp16 implicit GEMM ----------
// block = 256 threads = 4 waves; wave wid owns output row yb+wid, 32 cols, CO_I*16 couts.
// block tile: (CO_I*16) couts x 4 rows x 32 cols.
// LDS per buffer: 6 rows x 4 sg x 34 cols x 16B = 13056 B; 2 buffers (dbuf).
// T3 2-phase: stage(next) -> compute(cur) -> barrier.
// All convs VALID-style (rnn uses zeroed halo buffer); OOB-ish reads land in
// allocation slack and only feed store-masked dead outputs (no NaN in fp16 poison).
template<int CINP, int CO_I, bool RELU, bool K3>
__global__ __launch_bounds__(256, 3) void conv3(
    const _Float16* __restrict__ X, int Wst, unsigned xbstr,
    const _Float16* __restrict__ Wp, int COUTP,
    const float* __restrict__ bias,
    _Float16* __restrict__ Y, int Wst_out, int DCP, unsigned ybstr,
    unsigned* __restrict__ slot, int Ho, int Wo,
    int nco_mask, int nco_shift)
{
  constexpr int KC = CINP/32;
  __shared__ _Float16 lds[2][6528];

  const int tid  = threadIdx.x;
  const int lane = tid & 63;
  const int wid  = tid >> 6;
  const int l15  = lane & 15, lg = lane >> 4;
  const int xb   = blockIdx.x * 32;
  const int yb   = blockIdx.y * 4;
  const int co_blk = blockIdx.z & nco_mask;
  const int b      = blockIdx.z >> nco_shift;
  const int co_base = co_blk * (CO_I*16);

  const _Float16* Xb = X + (size_t)b * xbstr;

  // stage addresses: 816 16B items = [row 6][sg 4][col 34]
  uint32_t goff[4];
  #pragma unroll
  for (int k = 0; k < 4; ++k){
    int item = k*256 + tid;
    int col = item % 34;
    int q   = item / 34;
    int sg  = q & 3;
    int row = q >> 2;
    int pix = (yb + row)*Wst + xb + col;
    goff[k] = (uint32_t)(((uint32_t)pix*CINP + sg*8) * 2);   // bytes
  }

  auto stage = [&](int buf, int kc){
    const char* xp = (const char*)Xb + (size_t)kc*64;        // +32 channels
    char* lb = (char*)&lds[buf][0];
    #pragma unroll
    for (int k = 0; k < 3; ++k)
      gload16(xp + goff[k], lb + k*4096 + wid*1024);
    if (tid < 48)
      gload16(xp + goff[3], lb + 3*4096 + wid*1024);
  };

  f32x4 acc[CO_I][2] = {};
  const _Float16* wlane = Wp + (size_t)(co_base + l15)*CINP + lg*8;

  stage(0, 0);
  __syncthreads();
  for (int kc = 0; kc < KC; ++kc){
    if (kc + 1 < KC) stage((kc+1)&1, kc+1);
    const _Float16* lb = &lds[kc&1][0];
    #pragma unroll
    for (int ky = 0; ky < 3; ++ky){
      #pragma unroll
      for (int kx = 0; kx < 3; ++kx){
        const _Float16* wt = wlane + (size_t)(ky*3+kx)*COUTP*CINP + kc*32;
        half8 a[CO_I];
        #pragma unroll
        for (int i = 0; i < CO_I; ++i)
          a[i] = *reinterpret_cast<const half8*>(wt + (size_t)i*16*CINP);
        const int ldsrow = ((wid + ky)*4 + lg)*34;
        #pragma unroll
        for (int n = 0; n < 2; ++n){
          half8 bfrag = *reinterpret_cast<const half8*>(lb + (ldsrow + n*16 + l15 + kx)*8);
          #pragma unroll
          for (int i = 0; i < CO_I; ++i)
            acc[i][n] = __builtin_amdgcn_mfma_f32_16x16x32_f16(a[i], bfrag, acc[i][n], 0, 0, 0);
        }
      }
    }
    if (kc + 1 < KC) __syncthreads();
  }

  // ---- epilogue ----
  const int y = yb + wid;
  float lmax = -3.0e38f;
  if (y < Ho){
    #pragma unroll
    for (int i = 0; i < CO_I; ++i){
      const int cb = co_base + i*16 + lg*4;       // 4 consecutive output channels
      f32x4 bs = *reinterpret_cast<const f32x4*>(bias + cb);
      #pragma unroll
      for (int n = 0; n < 2; ++n){
        const int x = xb + n*16 + l15;
        if (x < Wo){
          float v[4];
          #pragma unroll
          for (int j = 0; j < 4; ++j){
            float t = acc[i][n][j] + bs[j];
            if (RELU) t = t > 0.f ? t : 0.01f*t;
            v[j] = t;
          }
          if constexpr (!K3){
            half4 pk;
            #pragma unroll
            for (int j = 0; j < 4; ++j) pk[j] = (_Float16)v[j];
            *reinterpret_cast<half4*>(Y + (size_t)b*ybstr + ((size_t)y*Wst_out + x)*DCP + cb) = pk;
          } else {
            _Float16* yp = Y + (size_t)b*ybstr;
            #pragma unroll
            for (int j = 0; j < 4; ++j){
              if (cb + j < 441){
                yp[(size_t)(cb+j)*34596 + (size_t)y*186 + x] = (_Float16)v[j];
                lmax = fmaxf(lmax, v[j]);
              }
            }
          }
        }
      }
    }
  }
  if constexpr (K3){
    #pragma unroll
    for (int o = 32; o > 0; o >>= 1) lmax = fmaxf(lmax, __shfl_xor(lmax, o));
    if (lane == 0) atomicMax(slot + b, encf(lmax));
  }
}

// streaming-max state update per batch: st[2b]=M, st[2b+1]=scale; resets slot
__global__ void update_max(float* __restrict__ st, unsigned* __restrict__ slot, int step){
  int b = threadIdx.x;
  if (b < 2){
    float nm   = decf(slot[b]);
    float oldM = st[2*b];
    float M    = (step == 0) ? nm : fmaxf(oldM, nm);
    st[2*b+1] = (step == 0) ? 0.f : expf(oldM - M);
    st[2*b]   = M;
    slot[b] = 0u;
  }
}

// per-pixel: w_t = exp(k3[t][y+7][x+7]-M); unnorm = unnorm*scale + sum_t w_t*rad
__global__ __launch_bounds__(256) void apply_acc(
    const _Float16* __restrict__ k3out, const float* __restrict__ rad,
    const float* __restrict__ st,
    float* __restrict__ unnorm, float* __restrict__ sumw)
{
  const int tx = threadIdx.x & 63, ty = threadIdx.x >> 6;
  const int x = blockIdx.x*64 + tx;
  const int y = blockIdx.y*4 + ty;
  const int b = blockIdx.z;
  if (x >= 172 || y >= 172) return;
  const float M = st[2*b], scale = st[2*b+1];
  const _Float16* kp = k3out + (size_t)b*15256836 + (size_t)(y+7)*186 + (x+7);
  const float* rb = rad + (size_t)b*884736;          // 8*3*36864
  float a0 = 0.f, a1 = 0.f, a2 = 0.f, aw = 0.f;
  for (int dy = 0; dy < 21; ++dy){
    const float* r0 = rb + (size_t)(y+dy)*192 + x;
    #pragma unroll
    for (int dx = 0; dx < 21; ++dx){
      float w = __expf((float)kp[(size_t)(dy*21+dx)*34596] - M);
      aw += w;
      a0 += w * r0[dx];
      a1 += w * r0[36864 + dx];
      a2 += w * r0[73728 + dx];
    }
  }
  size_t p = (size_t)b*88752 + (size_t)y*172 + x;
  size_t ps = (size_t)b*29584 + (size_t)y*172 + x;
  unnorm[p]        = unnorm[p]*scale        + a0;
  unnorm[p+29584]  = unnorm[p+29584]*scale  + a1;
  unnorm[p+59168]  = unnorm[p+59168]*scale  + a2;
  sumw[ps]         = sumw[ps]*scale         + aw;
}

__global__ __launch_bounds__(256) void finalize_out(const float* __restrict__ unnorm,
                                                    const float* __restrict__ sumw,
                                                    float* __restrict__ out){
  int i = blockIdx.x*256 + threadIdx.x;
  int b = blockIdx.y;
  if (i >= 88752) return;
  int p = i % 29584;
  out[(size_t)b*88752 + i] = unnorm[(size_t)b*88752 + i] / (sumw[(size_t)b*29584 + p] + 1e-8f);
}

// ---------- host ----------
extern "C" void kernel_launch(void* const* d_in, const int* in_sizes, int n_in,
                              void* d_out, int out_size, void* d_ws, size_t ws_size,
                              hipStream_t stream) {
  const float* features = (const float*)d_in[0];
  const float* radiance = (const float*)d_in[1];
  const float* w_rnn = (const float*)d_in[2];
  const float* b_rnn = (const float*)d_in[3];
  const float* w_k1  = (const float*)d_in[4];
  const float* b_k1  = (const float*)d_in[5];
  const float* w_k2  = (const float*)d_in[6];
  const float* b_k2  = (const float*)d_in[7];
  const float* w_k3  = (const float*)d_in[8];
  const float* b_k3  = (const float*)d_in[9];
  float* out = (float*)d_out;

  char* ws = (char*)d_ws;
  size_t off = 0;
  auto alloc = [&](size_t bytes)->char*{
    char* p = ws + off;
    off = (off + bytes + 255) & ~(size_t)255;
    return p;
  };
  _Float16* wp_rnn   = (_Float16*)alloc((size_t)9*128*160*2);
  _Float16* wp_k1    = (_Float16*)alloc((size_t)9*128*160*2);
  _Float16* wp_k2    = (_Float16*)alloc((size_t)9*128*128*2);
  _Float16* wp_k3    = (_Float16*)alloc((size_t)9*448*128*2);
  float*    bias_k3p = (float*)   alloc((size_t)448*4);
  // per-batch strides (elements)
  const unsigned RB = 194u*194u*160u;          // rnn_in
  const unsigned KB = (192u*192u+448u)*160u;   // k1_in
  const unsigned K2B = (190u*190u+444u)*128u;  // k2_in
  const unsigned K3B = (188u*188u+440u)*128u;  // k3_in
  const unsigned KOB = 441u*34596u;            // k3_out
  _Float16* rnn_in = (_Float16*)alloc((size_t)2*RB*2);
  _Float16* k1_in  = (_Float16*)alloc((size_t)2*KB*2);
  _Float16* k2_in  = (_Float16*)alloc((size_t)2*K2B*2);
  _Float16* k3_in  = (_Float16*)alloc((size_t)2*K3B*2);
  _Float16* k3_out = (_Float16*)alloc((size_t)2*KOB*2);
  float*    accz   = (float*)   alloc((size_t)236678*4);
  if (off > ws_size) return;  // workspace too small -> fail loudly (no OOB writes)

  float*    unnorm = accz;                 // [2][3][172][172]
  float*    sumw   = accz + 177504;        // [2][172][172]
  float*    st     = accz + 236672;        // [2][{M,scale}]
  unsigned* slot   = (unsigned*)(accz + 236676);  // [2]

  // weight prepack (pure function of inputs; runs every call)
  pack_w<<<(9*128*160+255)/256, 256, 0, stream>>>(w_rnn, wp_rnn, 128, 144, 128, 160);
  pack_w<<<(9*128*160+255)/256, 256, 0, stream>>>(w_k1,  wp_k1,  128, 144, 128, 160);
  pack_w<<<(9*128*128+255)/256, 256, 0, stream>>>(w_k2,  wp_k2,  128, 128, 128, 128);
  pack_w<<<(9*448*128+255)/256, 256, 0, stream>>>(w_k3,  wp_k3,  441, 128, 448, 128);
  pack_bias<<<2, 256, 0, stream>>>(b_k3, bias_k3p, 441, 448);

  // zero rnn halo+state (both batches) and accumulators
  zero_u32<<<2048, 256, 0, stream>>>((unsigned*)rnn_in, (int)(2*RB/2));
  zero_u32<<<925,  256, 0, stream>>>((unsigned*)accz, 236678);

  for (int s = 0; s < 8; ++s){
    const float* f   = features + (size_t)s*16*36864;   // batch stride 8*16*36864
    const float* rad = radiance + (size_t)s*3*36864;    // batch stride 8*3*36864
    pack_feat<<<dim3(144,2), 256, 0, stream>>>(f, rnn_in, k1_in, s > 0 ? 1 : 0,
                                               8u*16u*36864u, RB, KB);
    // rnn: 144(160)->128 SAME via zero halo, lrelu; -> k1_in ch0..127
    conv3<160,8,true ,false><<<dim3(6,48,2), 256, 0, stream>>>(
        rnn_in, 194, RB, wp_rnn, 128, b_rnn, k1_in, 192, 160, KB,
        nullptr, 192, 192, 0, 0);
    // k1: 144(160)->128 VALID, lrelu; -> k2_in (190x190)
    conv3<160,8,true ,false><<<dim3(6,48,2), 256, 0, stream>>>(
        k1_in, 192, KB, wp_k1, 128, b_k1, k2_in, 190, 128, K2B,
        nullptr, 190, 190, 0, 0);
    // k2: 128->128 VALID, lrelu; -> k3_in (188x188)
    conv3<128,8,true ,false><<<dim3(6,47,2), 256, 0, stream>>>(
        k2_in, 190, K2B, wp_k2, 128, b_k2, k3_in, 188, 128, K3B,
        nullptr, 188, 188, 0, 0);
    // k3: 128->441(448) VALID, no relu; -> fp16 planes + atomic max (4 co-slices x 2 batches)
    conv3<128,7,false,true ><<<dim3(6,47,8), 256, 0, stream>>>(
        k3_in, 188, K3B, wp_k3, 448, bias_k3p, k3_out, 0, 0, KOB,
        slot, 186, 186, 3, 2);
    update_max<<<1, 64, 0, stream>>>(st, slot, s);
    apply_acc<<<dim3(3,43,2), 256, 0, stream>>>(k3_out, rad, st, unnorm, sumw);
  }
  finalize_out<<<dim3(347,2), 256, 0, stream>>>(unnorm, sumw, out);
}

// Round 5
// 2739.187 us; speedup vs baseline: 5.5515x; 1.8708x over previous
//
#include <hip/hip_runtime.h>
#include <stdint.h>

typedef _Float16 half8 __attribute__((ext_vector_type(8)));
typedef _Float16 half4 __attribute__((ext_vector_type(4)));
typedef __attribute__((ext_vector_type(8))) short short8;
typedef __attribute__((ext_vector_type(4))) float f32x4;

// ---------- helpers ----------
__device__ __forceinline__ unsigned encf(float x){                // monotonic f32->u32
  uint32_t u = __float_as_uint(x);
  return (u & 0x80000000u) ? ~u : (u | 0x80000000u);
}
__device__ __forceinline__ float decf(unsigned u){
  uint32_t b = (u & 0x80000000u) ? (u & 0x7FFFFFFFu) : ~u;
  return __uint_as_float(b);
}
__device__ __forceinline__ void gload16(const void* g, void* l){
  __builtin_amdgcn_global_load_lds(
      (const __attribute__((address_space(1))) void*)g,
      (__attribute__((address_space(3))) void*)l, 16, 0, 0);
}

// ---------- small utility kernels ----------
__global__ __launch_bounds__(256) void zero_u32(unsigned* __restrict__ p, int n){
  for (int i = blockIdx.x*256 + threadIdx.x; i < n; i += gridDim.x*256) p[i] = 0u;
}

// w (f32, [CO][CI][3][3]) -> wp (fp16, [kc][tap][COP][32]) zero-padded, contiguous
// per-(kc,tap) 64B-per-co chunks for streaming a-frag loads.
__global__ __launch_bounds__(256) void pack_w(const float* __restrict__ w, _Float16* __restrict__ wp,
                                              int CO, int CI, int COP, int CINP){
  int idx = blockIdx.x*256 + threadIdx.x;
  int total = 9*COP*CINP;
  if (idx >= total) return;
  int ci = idx % CINP;
  int rest = idx / CINP;
  int co = rest % COP;
  int t  = rest / COP;
  float v = 0.f;
  if (co < CO && ci < CI) v = w[((size_t)co*CI + ci)*9 + t];
  int kc = ci >> 5, cr = ci & 31;
  wp[(((size_t)kc*9 + t)*COP + co)*32 + cr] = (_Float16)v;
}

__global__ __launch_bounds__(256) void pack_bias(const float* __restrict__ b, float* __restrict__ bp, int n, int npad){
  int i = blockIdx.x*256 + threadIdx.x;
  if (i < npad) bp[i] = (i < n) ? b[i] : 0.f;
}

// features f32 [16][36864] -> rnn_in (halo 194x194, interior at +1,+1) ch0..15
//                             k1_in (192x192) ch128..143
// if copy_state: k1_in ch0..127 (state) -> rnn_in ch16..143. batch = blockIdx.y.
__global__ __launch_bounds__(256) void pack_feat(const float* __restrict__ f,
                                                 _Float16* __restrict__ rnn_in,
                                                 _Float16* __restrict__ k1_in,
                                                 int copy_state,
                                                 unsigned fbstr, unsigned rbstr, unsigned kbstr){
  int p = blockIdx.x*256 + threadIdx.x;
  if (p >= 36864) return;
  int b = blockIdx.y;
  int y = p / 192, x = p % 192;
  const float* fb = f + (size_t)b*fbstr;
  _Float16* r = rnn_in + (size_t)b*rbstr + ((size_t)(y+1)*194 + (x+1))*160;
  _Float16* k = k1_in  + (size_t)b*kbstr + (size_t)p*160;
  #pragma unroll
  for (int c = 0; c < 16; ++c){
    _Float16 v = (_Float16)fb[c*36864 + p];
    r[c] = v;
    k[128 + c] = v;
  }
  if (copy_state){
    #pragma unroll
    for (int cc = 0; cc < 128; cc += 8)
      *reinterpret_cast<short8*>(r + 16 + cc) = *reinterpret_cast<const short8*>(k + cc);
  }
}

// ---------- conv3x3: LDS double-buffered fp16 implicit GEMM ----------
// block = 256 threads = 4 waves: wm = wid&1 (co half), wq = wid>>1 (row pair).
// block tile: 128 co x 4 rows x 32 cols; wave tile: 64 co (C=4) x 2 rows x 32 cols (N=4).
// Weights: packed [kc][tap][COP][32ch] in global; per-tap contiguous 4KB/wave stream,
//   2-deep register ping-pong (load tap t+1 while MFMAing tap t).
// Acts: LDS dbuf, per buffer [row6][sg4][col34][16B] = 13056 B, staged via global_load_lds.
// All convs VALID-style (rnn uses zeroed halo buffer); OOB-ish reads land in
// allocation slack and only feed store-masked dead outputs.
template<int CINP, bool RELU, bool K3>
__global__ __launch_bounds__(256, 3) void conv3(
    const _Float16* __restrict__ X, int Wst, unsigned xbstr,
    const _Float16* __restrict__ Wp, int COP,
    const float* __restrict__ bias,
    _Float16* __restrict__ Y, int Wst_out, int DCP, unsigned ybstr,
    unsigned* __restrict__ slot, int Ho, int Wo,
    int nco_mask, int nco_shift)
{
  constexpr int KC = CINP/32;
  __shared__ _Float16 lds[2][6528];

  const int tid  = threadIdx.x;
  const int lane = tid & 63;
  const int wid  = tid >> 6;
  const int wm   = wid & 1;
  const int wq   = wid >> 1;
  const int l15  = lane & 15, lg = lane >> 4;
  const int xb   = blockIdx.x * 32;
  const int yb   = blockIdx.y * 4;
  const int co_blk = blockIdx.z & nco_mask;
  const int b      = blockIdx.z >> nco_shift;
  const int co_base = co_blk * 128;

  const _Float16* Xb = X + (size_t)b * xbstr;

  // stage addresses: 816 16B items = [row 6][sg 4][col 34]
  uint32_t goff[4];
  #pragma unroll
  for (int k = 0; k < 4; ++k){
    int item = k*256 + tid;
    int col = item % 34;
    int q   = item / 34;
    int sg  = q & 3;
    int row = q >> 2;
    int pix = (yb + row)*Wst + xb + col;
    goff[k] = (uint32_t)(((uint32_t)pix*CINP + sg*8) * 2);   // bytes
  }

  auto stage = [&](int buf, int kc){
    const char* xp = (const char*)Xb + (size_t)kc*64;        // +32 channels
    char* lb = (char*)&lds[buf][0];
    #pragma unroll
    for (int k = 0; k < 3; ++k)
      gload16(xp + goff[k], lb + k*4096 + wid*1024);
    if (tid < 48)
      gload16(xp + goff[3], lb + 3*4096 + wid*1024);
  };

  f32x4 acc[4][4] = {};
  // wave-lane weight base: co = co_base + wm*64 + l15, ch sub = lg*8
  const _Float16* wlane = Wp + ((size_t)(co_base + wm*64 + l15)*32 + lg*8);
  const size_t wtap = (size_t)COP*32;

  stage(0, 0);
  __syncthreads();
  for (int kc = 0; kc < KC; ++kc){
    if (kc + 1 < KC) stage((kc+1)&1, kc+1);
    const _Float16* wt = wlane + (size_t)kc*9*wtap;
    const _Float16* lb = &lds[kc&1][0];
    half8 wreg[2][4];
    #pragma unroll
    for (int i = 0; i < 4; ++i)
      wreg[0][i] = *reinterpret_cast<const half8*>(wt + (size_t)i*512);
    #pragma unroll
    for (int t = 0; t < 9; ++t){
      const int cur = t & 1, nxt = cur ^ 1;
      if (t < 8){
        const _Float16* wn = wt + (size_t)(t+1)*wtap;
        #pragma unroll
        for (int i = 0; i < 4; ++i)
          wreg[nxt][i] = *reinterpret_cast<const half8*>(wn + (size_t)i*512);
      }
      const int ky = t/3, kx = t - ky*3;
      #pragma unroll
      for (int n = 0; n < 4; ++n){
        const int row = wq*2 + (n>>1) + ky;
        const int ui = ((row*4 + lg)*34 + (n&1)*16 + l15 + kx)*8;
        half8 bfrag = *reinterpret_cast<const half8*>(lb + ui);
        #pragma unroll
        for (int i = 0; i < 4; ++i)
          acc[i][n] = __builtin_amdgcn_mfma_f32_16x16x32_f16(wreg[cur][i], bfrag, acc[i][n], 0, 0, 0);
      }
    }
    if (kc + 1 < KC) __syncthreads();
  }

  // ---- epilogue ----
  float lmax = -3.0e38f;
  #pragma unroll
  for (int i = 0; i < 4; ++i){
    const int cb = co_base + wm*64 + i*16 + lg*4;   // 4 consecutive output channels
    f32x4 bs = *reinterpret_cast<const f32x4*>(bias + cb);
    #pragma unroll
    for (int n = 0; n < 4; ++n){
      const int y = yb + wq*2 + (n>>1);
      const int x = xb + (n&1)*16 + l15;
      if (y < Ho && x < Wo){
        float v[4];
        #pragma unroll
        for (int j = 0; j < 4; ++j){
          float t = acc[i][n][j] + bs[j];
          if (RELU) t = t > 0.f ? t : 0.01f*t;
          v[j] = t;
        }
        if constexpr (!K3){
          half4 pk;
          #pragma unroll
          for (int j = 0; j < 4; ++j) pk[j] = (_Float16)v[j];
          *reinterpret_cast<half4*>(Y + (size_t)b*ybstr + ((size_t)y*Wst_out + x)*DCP + cb) = pk;
        } else {
          _Float16* yp = Y + (size_t)b*ybstr;
          #pragma unroll
          for (int j = 0; j < 4; ++j){
            if (cb + j < 441){
              yp[(size_t)(cb+j)*34596 + (size_t)y*186 + x] = (_Float16)v[j];
              lmax = fmaxf(lmax, v[j]);
            }
          }
        }
      }
    }
  }
  if constexpr (K3){
    #pragma unroll
    for (int o = 32; o > 0; o >>= 1) lmax = fmaxf(lmax, __shfl_xor(lmax, o));
    if (lane == 0) atomicMax(slot + b, encf(lmax));
  }
}

// streaming-max state update per batch: st[2b]=M, st[2b+1]=scale; resets slot
__global__ void update_max(float* __restrict__ st, unsigned* __restrict__ slot, int step){
  int b = threadIdx.x;
  if (b < 2){
    float nm   = decf(slot[b]);
    float oldM = st[2*b];
    float M    = (step == 0) ? nm : fmaxf(oldM, nm);
    st[2*b+1] = (step == 0) ? 0.f : expf(oldM - M);
    st[2*b]   = M;
    slot[b] = 0u;
  }
}

// per-pixel: w_t = exp(k3[t][y+7][x+7]-M); unnorm = unnorm*scale + sum_t w_t*rad
__global__ __launch_bounds__(256) void apply_acc(
    const _Float16* __restrict__ k3out, const float* __restrict__ rad,
    const float* __restrict__ st,
    float* __restrict__ unnorm, float* __restrict__ sumw)
{
  const int tx = threadIdx.x & 63, ty = threadIdx.x >> 6;
  const int x = blockIdx.x*64 + tx;
  const int y = blockIdx.y*4 + ty;
  const int b = blockIdx.z;
  if (x >= 172 || y >= 172) return;
  const float M = st[2*b], scale = st[2*b+1];
  const _Float16* kp = k3out + (size_t)b*15256836 + (size_t)(y+7)*186 + (x+7);
  const float* rb = rad + (size_t)b*884736;          // 8*3*36864
  float a0 = 0.f, a1 = 0.f, a2 = 0.f, aw = 0.f;
  for (int dy = 0; dy < 21; ++dy){
    const float* r0 = rb + (size_t)(y+dy)*192 + x;
    #pragma unroll
    for (int dx = 0; dx < 21; ++dx){
      float w = __expf((float)kp[(size_t)(dy*21+dx)*34596] - M);
      aw += w;
      a0 += w * r0[dx];
      a1 += w * r0[36864 + dx];
      a2 += w * r0[73728 + dx];
    }
  }
  size_t p = (size_t)b*88752 + (size_t)y*172 + x;
  size_t ps = (size_t)b*29584 + (size_t)y*172 + x;
  unnorm[p]        = unnorm[p]*scale        + a0;
  unnorm[p+29584]  = unnorm[p+29584]*scale  + a1;
  unnorm[p+59168]  = unnorm[p+59168]*scale  + a2;
  sumw[ps]         = sumw[ps]*scale         + aw;
}

__global__ __launch_bounds__(256) void finalize_out(const float* __restrict__ unnorm,
                                                    const float* __restrict__ sumw,
                                                    float* __restrict__ out){
  int i = blockIdx.x*256 + threadIdx.x;
  int b = blockIdx.y;
  if (i >= 88752) return;
  int p = i % 29584;
  out[(size_t)b*88752 + i] = unnorm[(size_t)b*88752 + i] / (sumw[(size_t)b*29584 + p] + 1e-8f);
}

// ---------- host ----------
extern "C" void kernel_launch(void* const* d_in, const int* in_sizes, int n_in,
                              void* d_out, int out_size, void* d_ws, size_t ws_size,
                              hipStream_t stream) {
  const float* features = (const float*)d_in[0];
  const float* radiance = (const float*)d_in[1];
  const float* w_rnn = (const float*)d_in[2];
  const float* b_rnn = (const float*)d_in[3];
  const float* w_k1  = (const float*)d_in[4];
  const float* b_k1  = (const float*)d_in[5];
  const float* w_k2  = (const float*)d_in[6];
  const float* b_k2  = (const float*)d_in[7];
  const float* w_k3  = (const float*)d_in[8];
  const float* b_k3  = (const float*)d_in[9];
  float* out = (float*)d_out;

  char* ws = (char*)d_ws;
  size_t off = 0;
  auto alloc = [&](size_t bytes)->char*{
    char* p = ws + off;
    off = (off + bytes + 255) & ~(size_t)255;
    return p;
  };
  _Float16* wp_rnn   = (_Float16*)alloc((size_t)9*128*160*2);
  _Float16* wp_k1    = (_Float16*)alloc((size_t)9*128*160*2);
  _Float16* wp_k2    = (_Float16*)alloc((size_t)9*128*128*2);
  _Float16* wp_k3    = (_Float16*)alloc((size_t)9*512*128*2);
  float*    bias_k3p = (float*)   alloc((size_t)512*4);
  // per-batch strides (elements)
  const unsigned RB = 194u*194u*160u;          // rnn_in
  const unsigned KB = (192u*192u+448u)*160u;   // k1_in
  const unsigned K2B = (190u*190u+444u)*128u;  // k2_in
  const unsigned K3B = (188u*188u+440u)*128u;  // k3_in
  const unsigned KOB = 441u*34596u;            // k3_out
  _Float16* rnn_in = (_Float16*)alloc((size_t)2*RB*2);
  _Float16* k1_in  = (_Float16*)alloc((size_t)2*KB*2);
  _Float16* k2_in  = (_Float16*)alloc((size_t)2*K2B*2);
  _Float16* k3_in  = (_Float16*)alloc((size_t)2*K3B*2);
  _Float16* k3_out = (_Float16*)alloc((size_t)2*KOB*2);
  float*    accz   = (float*)   alloc((size_t)236678*4);
  if (off > ws_size) return;  // workspace too small -> fail loudly (no OOB writes)

  float*    unnorm = accz;                 // [2][3][172][172]
  float*    sumw   = accz + 177504;        // [2][172][172]
  float*    st     = accz + 236672;        // [2][{M,scale}]
  unsigned* slot   = (unsigned*)(accz + 236676);  // [2]

  // weight prepack (pure function of inputs; runs every call)
  pack_w<<<(9*128*160+255)/256, 256, 0, stream>>>(w_rnn, wp_rnn, 128, 144, 128, 160);
  pack_w<<<(9*128*160+255)/256, 256, 0, stream>>>(w_k1,  wp_k1,  128, 144, 128, 160);
  pack_w<<<(9*128*128+255)/256, 256, 0, stream>>>(w_k2,  wp_k2,  128, 128, 128, 128);
  pack_w<<<(9*512*128+255)/256, 256, 0, stream>>>(w_k3,  wp_k3,  441, 128, 512, 128);
  pack_bias<<<2, 256, 0, stream>>>(b_k3, bias_k3p, 441, 512);

  // zero rnn halo+state (both batches) and accumulators
  zero_u32<<<2048, 256, 0, stream>>>((unsigned*)rnn_in, (int)(2*RB/2));
  zero_u32<<<925,  256, 0, stream>>>((unsigned*)accz, 236678);

  for (int s = 0; s < 8; ++s){
    const float* f   = features + (size_t)s*16*36864;   // batch stride 8*16*36864
    const float* rad = radiance + (size_t)s*3*36864;    // batch stride 8*3*36864
    pack_feat<<<dim3(144,2), 256, 0, stream>>>(f, rnn_in, k1_in, s > 0 ? 1 : 0,
                                               8u*16u*36864u, RB, KB);
    // rnn: 144(160)->128 SAME via zero halo, lrelu; -> k1_in ch0..127
    conv3<160,true ,false><<<dim3(6,48,2), 256, 0, stream>>>(
        rnn_in, 194, RB, wp_rnn, 128, b_rnn, k1_in, 192, 160, KB,
        nullptr, 192, 192, 0, 0);
    // k1: 144(160)->128 VALID, lrelu; -> k2_in (190x190)
    conv3<160,true ,false><<<dim3(6,48,2), 256, 0, stream>>>(
        k1_in, 192, KB, wp_k1, 128, b_k1, k2_in, 190, 128, K2B,
        nullptr, 190, 190, 0, 0);
    // k2: 128->128 VALID, lrelu; -> k3_in (188x188)
    conv3<128,true ,false><<<dim3(6,47,2), 256, 0, stream>>>(
        k2_in, 190, K2B, wp_k2, 128, b_k2, k3_in, 188, 128, K3B,
        nullptr, 188, 188, 0, 0);
    // k3: 128->441(512 pad, 4 slices) VALID, no relu; -> fp16 planes + atomic max
    conv3<128,false,true ><<<dim3(6,47,8), 256, 0, stream>>>(
        k3_in, 188, K3B, wp_k3, 512, bias_k3p, k3_out, 0, 0, KOB,
        slot, 186, 186, 3, 2);
    update_max<<<1, 64, 0, stream>>>(st, slot, s);
    apply_acc<<<dim3(3,43,2), 256, 0, stream>>>(k3_out, rad, st, unnorm, sumw);
  }
  finalize_out<<<dim3(347,2), 256, 0, stream>>>(unnorm, sumw, out);
}